// Round 10
// baseline (4187.445 us; speedup 1.0000x reference)
//
#include <hip/hip_runtime.h>

// Problem constants
#define BB 2048
#define TT 26
#define DIN 512
#define HH 512
#define EE 256
#define CC 97
#define SS 32
#define G4 2048   // 4*H
#define XK2 1024  // gates GEMM K: ctx(512) + h(512); ce folded into P lookup

typedef unsigned short u16;
typedef __bf16 bf16x8 __attribute__((ext_vector_type(8)));
typedef float f32x4 __attribute__((ext_vector_type(4)));

__device__ __forceinline__ float bf2f(u16 u) {
    return __uint_as_float(((unsigned int)u) << 16);
}
__device__ __forceinline__ u16 f2bf(float f) {  // RNE
    unsigned int u = __float_as_uint(f);
    u = u + 0x7FFFu + ((u >> 16) & 1u);
    return (u16)(u >> 16);
}
__device__ __forceinline__ float th_f(float x) {
    return 1.0f - 2.0f * __builtin_amdgcn_rcpf(__expf(2.0f * x) + 1.0f);
}
__device__ __forceinline__ float sig_f(float x) {
    return __builtin_amdgcn_rcpf(1.0f + __expf(-x));
}

// async global->LDS, 16B/lane; LDS base wave-uniform
__device__ __forceinline__ void async16(const u16* g, u16* l) {
    __builtin_amdgcn_global_load_lds(
        (const __attribute__((address_space(1))) unsigned int*)(g),
        (__attribute__((address_space(3))) unsigned int*)(l), 16, 0, 0);
}

// ---------------------------------------------------------------------------
// gemm128 (Hp): C[M,N] = A[M,K] @ W[N,K]^T, 128x128 tile, m97 staging, bf16
// out.  XCD-chunked bijective swizzle (grid (4,416)).  BK=64 (r9-verified).
// ---------------------------------------------------------------------------
__global__ __launch_bounds__(256) void gemm128(
    const u16* __restrict__ A, int lda,
    const u16* __restrict__ W,
    u16* __restrict__ Cout, int ldc, int K)
{
    __shared__ __align__(16) u16 As[2 * 128 * 32];   // 16 KB
    __shared__ __align__(16) u16 Ws[2 * 128 * 32];   // 16 KB

    const int tid  = threadIdx.x;
    const int lane = tid & 63;
    const int wave = tid >> 6;

    int b = blockIdx.y * 4 + blockIdx.x;        // grid (4,416)
    int swz = (b & 7) * 208 + (b >> 3);         // XCD-chunked, bijective
    const int m0 = (swz >> 2) * 128;
    const int n0 = (swz & 3) * 128;

    const int srow = tid >> 2;
    const int scol = (tid & 3) * 8;
    const u16* Arow0 = A + (size_t)(m0 + srow) * lda + scol;
    const u16* Arow1 = A + (size_t)(m0 + 64 + srow) * lda + scol;
    const u16* Wrow0 = W + (size_t)(n0 + srow) * K + scol;
    const u16* Wrow1 = W + (size_t)(n0 + 64 + srow) * K + scol;

    const int wm = (wave >> 1) * 64;
    const int wn = (wave & 1) * 64;
    const int fr = lane & 15;
    const int fq = lane >> 4;

    f32x4 acc[4][4];
    #pragma unroll
    for (int i = 0; i < 4; i++)
        #pragma unroll
        for (int j = 0; j < 4; j++)
            #pragma unroll
            for (int r = 0; r < 4; r++) acc[i][j][r] = 0.0f;

    for (int kb = 0; kb < K; kb += 64) {
        #pragma unroll
        for (int cc = 0; cc < 2; cc++) {
            int k0 = kb + cc * 32;
            async16(Arow0 + k0, As + cc * 4096 + wave * 512);
            async16(Arow1 + k0, As + cc * 4096 + 2048 + wave * 512);
            async16(Wrow0 + k0, Ws + cc * 4096 + wave * 512);
            async16(Wrow1 + k0, Ws + cc * 4096 + 2048 + wave * 512);
        }
        __syncthreads();
        #pragma unroll
        for (int cc = 0; cc < 2; cc++) {
            const u16* A_ = As + cc * 4096;
            const u16* W_ = Ws + cc * 4096;
            bf16x8 af[4], bw[4];
            #pragma unroll
            for (int i = 0; i < 4; i++)
                af[i] = *(const bf16x8*)&A_[(wm + i * 16 + fr) * 32 + fq * 8];
            #pragma unroll
            for (int j = 0; j < 4; j++)
                bw[j] = *(const bf16x8*)&W_[(wn + j * 16 + fr) * 32 + fq * 8];
            #pragma unroll
            for (int i = 0; i < 4; i++)
                #pragma unroll
                for (int j = 0; j < 4; j++)
                    acc[i][j] = __builtin_amdgcn_mfma_f32_16x16x32_bf16(
                        af[i], bw[j], acc[i][j], 0, 0, 0);
        }
        __syncthreads();
    }

    #pragma unroll
    for (int j = 0; j < 4; j++) {
        int col = n0 + wn + j * 16 + fr;
        #pragma unroll
        for (int i = 0; i < 4; i++) {
            int row = m0 + wm + i * 16 + fq * 4;
            #pragma unroll
            for (int r = 0; r < 4; r++)
                Cout[(size_t)(row + r) * ldc + col] = f2bf(acc[i][j][r]);
        }
    }
}

// ---------------------------------------------------------------------------
// gen128: probs = hid[1..32] @ Wgen^T + b_gen.  grid (1, 512).  BK=64.
// ---------------------------------------------------------------------------
__global__ __launch_bounds__(256) void gen128(
    const u16* __restrict__ A,
    const u16* __restrict__ Wg,
    const float* __restrict__ bgen,
    float* __restrict__ out)
{
    __shared__ __align__(16) u16 As[2 * 128 * 32];   // 16 KB
    __shared__ __align__(16) u16 Ws[2 * 128 * 32];   // 16 KB

    const int tid  = threadIdx.x;
    const int lane = tid & 63;
    const int wave = tid >> 6;
    const int m0 = blockIdx.y * 128;

    const int srow = tid >> 2;
    const int scol = (tid & 3) * 8;
    const u16* Arow0 = A + (size_t)(m0 + srow) * HH + scol;
    const u16* Arow1 = A + (size_t)(m0 + 64 + srow) * HH + scol;
    const u16* Wrow0 = Wg + (size_t)srow * HH + scol;
    const u16* Wrow1 = Wg + (size_t)(64 + srow) * HH + scol;

    const int wm = (wave >> 1) * 64;
    const int wn = (wave & 1) * 64;
    const int fr = lane & 15;
    const int fq = lane >> 4;

    f32x4 acc[4][4];
    #pragma unroll
    for (int i = 0; i < 4; i++)
        #pragma unroll
        for (int j = 0; j < 4; j++)
            #pragma unroll
            for (int r = 0; r < 4; r++) acc[i][j][r] = 0.0f;

    #pragma unroll
    for (int kb = 0; kb < HH; kb += 64) {
        #pragma unroll
        for (int cc = 0; cc < 2; cc++) {
            int k0 = kb + cc * 32;
            async16(Arow0 + k0, As + cc * 4096 + wave * 512);
            async16(Arow1 + k0, As + cc * 4096 + 2048 + wave * 512);
            async16(Wrow0 + k0, Ws + cc * 4096 + wave * 512);
            async16(Wrow1 + k0, Ws + cc * 4096 + 2048 + wave * 512);
        }
        __syncthreads();
        #pragma unroll
        for (int cc = 0; cc < 2; cc++) {
            const u16* A_ = As + cc * 4096;
            const u16* W_ = Ws + cc * 4096;
            bf16x8 af[4], bw[4];
            #pragma unroll
            for (int i = 0; i < 4; i++)
                af[i] = *(const bf16x8*)&A_[(wm + i * 16 + fr) * 32 + fq * 8];
            #pragma unroll
            for (int j = 0; j < 4; j++)
                bw[j] = *(const bf16x8*)&W_[(wn + j * 16 + fr) * 32 + fq * 8];
            #pragma unroll
            for (int i = 0; i < 4; i++)
                #pragma unroll
                for (int j = 0; j < 4; j++)
                    acc[i][j] = __builtin_amdgcn_mfma_f32_16x16x32_bf16(
                        af[i], bw[j], acc[i][j], 0, 0, 0);
        }
        __syncthreads();
    }

    #pragma unroll
    for (int j = 0; j < 4; j++) {
        int col = wn + j * 16 + fr;
        if (col < CC) {
            float bv = bgen[col];
            #pragma unroll
            for (int i = 0; i < 4; i++) {
                int row = m0 + wm + i * 16 + fq * 4;
                #pragma unroll
                for (int r = 0; r < 4; r++) {
                    int m = row + r;
                    int s = m >> 11, b = m & (BB - 1);
                    out[(size_t)b * (SS * CC) + s * CC + col] = acc[i][j][r] + bv;
                }
            }
        }
    }
}

// ---------------------------------------------------------------------------
// gates_lstm: gates = [ctx|h_s] @ Wcat^T (interleaved col=4h+g), fused LSTM,
// BK=128 (r8-verified), 2 blocks/CU.
// r10: FUSED ph phase -- after the LSTM epilogue, each block arrives at a
// per-strip counter (16 blocks cover one 64-row strip); once all 16 have
// published hnext (device-scope release), each block computes its 64x32 tile
// of ph = hnext @ W_h2h^T + b_h2h for the NEXT step.  Replaces the ph64
// dispatch + one serial boundary per step.  Spin has a timeout (failure =>
// wrong answer caught by harness, never a hang).  rocprof-replay safe
// (counter >= 16 falls through).  Last step skips the phase.
// ---------------------------------------------------------------------------
__global__ __launch_bounds__(256) void gates_lstm(
    const u16* __restrict__ ctx,    // [B][512]
    const u16* __restrict__ hprev,  // [B][512] (hid slot s)
    const u16* __restrict__ Wc,     // [2048][1024] interleaved
    const float* __restrict__ bcat, // [2048] interleaved
    const float* __restrict__ P,    // [128][2048] char-gate bias, interleaved
    const int* __restrict__ text,   // [B][SS]
    float* __restrict__ c,          // [B][512]
    u16* __restrict__ hnext,        // [B][512] (hid slot s+1)
    int s,
    const u16* __restrict__ Wh2h,   // [512][512] bf16
    const float* __restrict__ bh2h, // [512] f32
    float* __restrict__ phout,      // [B][512] f32 (for step s+1)
    unsigned int* cnt)              // [SS][32] arrive counters (prep-zeroed)
{
    // staging: As[4][64*32] 16KB @0 | Ws[4][128*32] 32KB @16384; total 48KB.
    // epilogue: gsm[64][68] f32 (17408B) aliases the base after staging dies.
    // ph phase: Aps 16KB @0 | Wps 8KB @16384 (staging dead again).
    __shared__ __align__(16) char smem[49152];
    __shared__ int text_sm[64];

    u16* As = (u16*)smem;
    u16* Ws = (u16*)(smem + 16384);

    const int tid  = threadIdx.x;
    const int lane = tid & 63;
    const int wave = tid >> 6;

    // XCD swizzle: per-XCD 8x8 region (A 8 strips + W 8 strips < 4 MB L2)
    int b   = blockIdx.y * gridDim.x + blockIdx.x;
    int xcd = b & 7, loc = b >> 3;
    int by = (xcd & 3) * 8 + (loc & 7);     // 0..31  (M tiles)
    int bx = (xcd >> 2) * 8 + (loc >> 3);   // 0..15  (N tiles)
    const int m0 = by * 64;
    const int n0 = bx * 128;

    if (tid < 64) text_sm[tid] = text[(m0 + tid) * SS + s];

    const int srow = tid >> 2;
    const int scol = (tid & 3) * 8;
    const u16* Actx  = ctx   + (size_t)(m0 + srow) * 512 + scol;
    const u16* Ahid  = hprev + (size_t)(m0 + srow) * 512 + scol;
    const u16* Wrow0 = Wc + (size_t)(n0 + srow) * XK2 + scol;
    const u16* Wrow1 = Wc + (size_t)(n0 + 64 + srow) * XK2 + scol;

    const int wm = (wave & 1) * 32;   // 2x2 wave grid: 32M x 64N each
    const int wn = (wave >> 1) * 64;
    const int fr = lane & 15;
    const int fq = lane >> 4;

    f32x4 acc[2][4];
    #pragma unroll
    for (int i = 0; i < 2; i++)
        #pragma unroll
        for (int j = 0; j < 4; j++)
            #pragma unroll
            for (int r = 0; r < 4; r++) acc[i][j][r] = 0.0f;

    #pragma unroll
    for (int it = 0; it < 8; it++) {
        int kb = it * 128;
        #pragma unroll
        for (int cc = 0; cc < 4; cc++) {
            int k0 = kb + cc * 32;
            const u16* a = (k0 < 512) ? (Actx + k0) : (Ahid + (k0 - 512));
            async16(a, As + cc * 2048 + wave * 512);
            async16(Wrow0 + k0, Ws + cc * 4096 + wave * 512);
            async16(Wrow1 + k0, Ws + cc * 4096 + 2048 + wave * 512);
        }
        __syncthreads();
        #pragma unroll
        for (int cc = 0; cc < 4; cc++) {
            const u16* A_ = As + cc * 2048;
            const u16* W_ = Ws + cc * 4096;
            bf16x8 af[2], bw[4];
            #pragma unroll
            for (int i = 0; i < 2; i++)
                af[i] = *(const bf16x8*)&A_[(wm + i * 16 + fr) * 32 + fq * 8];
            #pragma unroll
            for (int j = 0; j < 4; j++)
                bw[j] = *(const bf16x8*)&W_[(wn + j * 16 + fr) * 32 + fq * 8];
            #pragma unroll
            for (int i = 0; i < 2; i++)
                #pragma unroll
                for (int j = 0; j < 4; j++)
                    acc[i][j] = __builtin_amdgcn_mfma_f32_16x16x32_bf16(
                        af[i], bw[j], acc[i][j], 0, 0, 0);
        }
        __syncthreads();
    }

    // Epilogue: two 64-col passes -> gsm (aliases staging), then fused LSTM
    float* gsm = (float*)smem;
    #pragma unroll
    for (int p = 0; p < 2; p++) {
        if ((wave >> 1) == p) {
            #pragma unroll
            for (int j = 0; j < 4; j++) {
                int cl = j * 16 + fr;
                #pragma unroll
                for (int i = 0; i < 2; i++) {
                    int rl = wm + i * 16 + fq * 4;
                    #pragma unroll
                    for (int r = 0; r < 4; r++)
                        gsm[(rl + r) * 68 + cl] = acc[i][j][r];
                }
            }
        }
        __syncthreads();
        #pragma unroll
        for (int rr = 0; rr < 4; rr++) {
            int idx = rr * 256 + tid;
            int u = idx & 15, row = idx >> 4;
            int base = row * 68 + 4 * u;
            int hg = (n0 >> 2) + p * 16 + u;   // global h unit
            int c0 = 4 * hg;                    // interleaved gate col base
            int ch = text_sm[row];
            float4 bc = *(const float4*)(bcat + c0);
            float4 pv = *(const float4*)(P + (size_t)ch * G4 + c0);
            float ig = sig_f(gsm[base]     + bc.x + pv.x);
            float fg = sig_f(gsm[base + 1] + bc.y + pv.y);
            float gg = th_f (gsm[base + 2] + bc.z + pv.z);
            float og = sig_f(gsm[base + 3] + bc.w + pv.w);
            size_t ci = (size_t)(m0 + row) * HH + hg;
            float cn = fg * c[ci] + ig * gg;
            c[ci] = cn;
            hnext[(size_t)(m0 + row) * HH + hg] = f2bf(og * th_f(cn));
        }
        __syncthreads();
    }

    // ---- fused ph phase (skip on last step) ----
    if (s != SS - 1) {
        // publish hnext tile; wait for the 15 sibling blocks of this strip
        if (tid == 0) {
            __threadfence();   // device-scope release of our hnext stores
            __hip_atomic_fetch_add(&cnt[s * 32 + by], 1u,
                                   __ATOMIC_RELEASE, __HIP_MEMORY_SCOPE_AGENT);
            int spin = 0;
            while (__hip_atomic_load(&cnt[s * 32 + by], __ATOMIC_ACQUIRE,
                                     __HIP_MEMORY_SCOPE_AGENT) < 16u &&
                   spin < (1 << 22)) {
                __builtin_amdgcn_s_sleep(4);
                ++spin;
            }
        }
        __syncthreads();
        __threadfence();       // device-scope acquire for all threads

        // ph tile: rows m0..m0+63, cols nc0..nc0+31  (M=64,N=32,K=512)
        const int nc0 = bx * 32;
        u16* Aps = (u16*)smem;             // 4 chunks x 4KB = 16KB
        u16* Wps = (u16*)(smem + 16384);   // 4 chunks x 2KB = 8KB
        const u16* Hrow  = hnext + (size_t)(m0 + srow) * 512 + scol;
        const u16* Wprow = Wh2h + (size_t)(nc0 + ((tid & 127) >> 2)) * 512 + scol;
        const int wm2 = wave * 16;

        f32x4 pacc[2];
        #pragma unroll
        for (int j = 0; j < 2; j++)
            #pragma unroll
            for (int r = 0; r < 4; r++) pacc[j][r] = 0.0f;

        #pragma unroll
        for (int win = 0; win < 4; win++) {
            int kb = win * 128;
            #pragma unroll
            for (int cc2 = 0; cc2 < 4; cc2++) {
                int k0 = kb + cc2 * 32;
                async16(Hrow + k0, Aps + cc2 * 2048 + wave * 512);
                if (wave < 2)
                    async16(Wprow + k0, Wps + cc2 * 1024 + wave * 512);
            }
            __syncthreads();
            #pragma unroll
            for (int cc2 = 0; cc2 < 4; cc2++) {
                bf16x8 af = *(const bf16x8*)
                    &Aps[cc2 * 2048 + (wm2 + fr) * 32 + fq * 8];
                #pragma unroll
                for (int j = 0; j < 2; j++) {
                    bf16x8 bw = *(const bf16x8*)
                        &Wps[cc2 * 1024 + (j * 16 + fr) * 32 + fq * 8];
                    pacc[j] = __builtin_amdgcn_mfma_f32_16x16x32_bf16(
                        af, bw, pacc[j], 0, 0, 0);
                }
            }
            __syncthreads();
        }

        #pragma unroll
        for (int j = 0; j < 2; j++) {
            int col = nc0 + j * 16 + fr;
            float bv = bh2h[col];
            int row = m0 + wm2 + fq * 4;
            #pragma unroll
            for (int r = 0; r < 4; r++)
                phout[(size_t)(row + r) * 512 + col] = pacc[j][r] + bv;
        }
    }
}

// ---------------------------------------------------------------------------
// gemm64: generic 64x64-tile GEMM (VGPR-staged).  One-time P build only.
// ---------------------------------------------------------------------------
__global__ __launch_bounds__(256) void gemm64(
    const u16* __restrict__ A, int lda,
    const u16* __restrict__ W, int ldw,
    const float* __restrict__ bias,
    float* __restrict__ Cout, int ldc, int K, int use_bias)
{
    __shared__ __align__(16) u16 As[64][32];
    __shared__ __align__(16) u16 Ws[64][32];

    const int tid  = threadIdx.x;
    const int lane = tid & 63;
    const int wave = tid >> 6;
    const int m0 = blockIdx.y * 64;
    const int n0 = blockIdx.x * 64;
    const int ar = tid >> 2;
    const int ac = (tid & 3) * 8;
    const int wm = (wave >> 1) * 32;
    const int wn = (wave & 1) * 32;
    const int fr = lane & 15;
    const int fq = lane >> 4;

    f32x4 acc[2][2];
    #pragma unroll
    for (int i = 0; i < 2; i++)
        #pragma unroll
        for (int j = 0; j < 2; j++)
            #pragma unroll
            for (int r = 0; r < 4; r++) acc[i][j][r] = 0.0f;

    const u16* Arow = A + (size_t)(m0 + ar) * lda;
    const u16* Wrow = W + (size_t)(n0 + ar) * ldw;

    for (int k0 = 0; k0 < K; k0 += 32) {
        *(uint4*)&As[ar][ac] = *(const uint4*)(Arow + k0 + ac);
        *(uint4*)&Ws[ar][ac] = *(const uint4*)(Wrow + k0 + ac);
        __syncthreads();
        bf16x8 af[2], bw[2];
        #pragma unroll
        for (int mm = 0; mm < 2; mm++)
            af[mm] = *(const bf16x8*)&As[wm + mm * 16 + fr][fq * 8];
        #pragma unroll
        for (int nn = 0; nn < 2; nn++)
            bw[nn] = *(const bf16x8*)&Ws[wn + nn * 16 + fr][fq * 8];
        #pragma unroll
        for (int mm = 0; mm < 2; mm++)
            #pragma unroll
            for (int nn = 0; nn < 2; nn++)
                acc[mm][nn] = __builtin_amdgcn_mfma_f32_16x16x32_bf16(
                    af[mm], bw[nn], acc[mm][nn], 0, 0, 0);
        __syncthreads();
    }

    #pragma unroll
    for (int nn = 0; nn < 2; nn++) {
        int col = n0 + wn + nn * 16 + fr;
        float bv = use_bias ? bias[col] : 0.0f;
        #pragma unroll
        for (int mm = 0; mm < 2; mm++) {
            int row = m0 + wm + mm * 16 + fq * 4;
            #pragma unroll
            for (int r = 0; r < 4; r++)
                Cout[(size_t)(row + r) * ldc + col] = acc[mm][nn][r] + bv;
        }
    }
}

// ---------------------------------------------------------------------------
// attn_step: e/softmax/context into ctx buffer.  1 block / batch row.
// (r2-verified: wave-parallel softmax, direct phase C)
// ---------------------------------------------------------------------------
__global__ __launch_bounds__(256) void attn_step(
    const u16* __restrict__ Hp, const float* __restrict__ ph,
    const float* __restrict__ wscore, const u16* __restrict__ bH16,
    u16* __restrict__ ctx)
{
    const int b = blockIdx.x;
    const int tid = threadIdx.x, lane = tid & 63, wave = tid >> 6;
    __shared__ float e_sm[32];
    __shared__ float alpha_sm[32];

    const int h8 = lane * 8;
    float ph_r[8], ws_r[8];
    {
        float4 p0 = *(const float4*)(ph + (size_t)b * HH + h8);
        float4 p1 = *(const float4*)(ph + (size_t)b * HH + h8 + 4);
        ph_r[0]=p0.x; ph_r[1]=p0.y; ph_r[2]=p0.z; ph_r[3]=p0.w;
        ph_r[4]=p1.x; ph_r[5]=p1.y; ph_r[6]=p1.z; ph_r[7]=p1.w;
        float4 w0 = *(const float4*)(wscore + h8);
        float4 w1 = *(const float4*)(wscore + h8 + 4);
        ws_r[0]=w0.x; ws_r[1]=w0.y; ws_r[2]=w0.z; ws_r[3]=w0.w;
        ws_r[4]=w1.x; ws_r[5]=w1.y; ws_r[6]=w1.z; ws_r[7]=w1.w;
    }

    for (int t = wave; t < TT; t += 4) {
        uint4 hv = *(const uint4*)(Hp + ((size_t)b * TT + t) * HH + h8);
        const u16* hu = (const u16*)&hv;
        float sum = 0.0f;
        #pragma unroll
        for (int j = 0; j < 8; j++)
            sum += th_f(bf2f(hu[j]) + ph_r[j]) * ws_r[j];
        #pragma unroll
        for (int off = 32; off > 0; off >>= 1) sum += __shfl_down(sum, off);
        if (lane == 0) e_sm[t] = sum;
    }
    __syncthreads();

    // wave-parallel softmax over t (wave 0 only)
    if (wave == 0) {
        float ev = (lane < TT) ? e_sm[lane] : -3.0e38f;
        float mx = ev;
        #pragma unroll
        for (int off = 32; off > 0; off >>= 1)
            mx = fmaxf(mx, __shfl_xor(mx, off));
        float p = (lane < TT) ? __expf(ev - mx) : 0.0f;
        float ssum = p;
        #pragma unroll
        for (int off = 32; off > 0; off >>= 1) ssum += __shfl_xor(ssum, off);
        if (lane < TT) alpha_sm[lane] = p / ssum;
    }
    __syncthreads();

    {
        int d0 = tid * 2;
        float c0 = 0.0f, c1 = 0.0f;
        const u16* bb = bH16 + (size_t)b * TT * DIN + d0;
        #pragma unroll
        for (int t = 0; t < TT; t++) {
            unsigned int v = *(const unsigned int*)(bb + (size_t)t * DIN);
            float a = alpha_sm[t];
            c0 += a * bf2f((u16)(v & 0xffffu));
            c1 += a * bf2f((u16)(v >> 16));
        }
        unsigned int o = (unsigned int)f2bf(c0) | ((unsigned int)f2bf(c1) << 16);
        *(unsigned int*)(ctx + (size_t)b * 512 + d0) = o;
    }
}

// ---------------------------------------------------------------------------
// prep: bH16 cast (separate, big) + prep_all (everything else, one launch)
// ---------------------------------------------------------------------------
__global__ __launch_bounds__(256) void cast_f32_bf16(
    const float* __restrict__ src, u16* __restrict__ dst, int n)
{
    int i = (blockIdx.x * 256 + threadIdx.x) * 4;
    if (i < n) {
        float4 v = *(const float4*)(src + i);
        ushort4 o;
        o.x = f2bf(v.x); o.y = f2bf(v.y); o.z = f2bf(v.z); o.w = f2bf(v.w);
        *(ushort4*)(dst + i) = o;
    }
}

__global__ __launch_bounds__(256) void prep_all(
    const float* __restrict__ W_ih, const float* __restrict__ W_hh,
    const float* __restrict__ b_ih, const float* __restrict__ b_hh,
    const float* __restrict__ b_h2h, const float* __restrict__ emb,
    const float* __restrict__ W_i2h, const float* __restrict__ W_h2h,
    const float* __restrict__ W_gen,
    u16* __restrict__ Wcat, u16* __restrict__ Wce16, u16* __restrict__ emb16,
    u16* __restrict__ Wgen16, u16* __restrict__ Wi2h16, u16* __restrict__ Wh2h16,
    float* __restrict__ bcat, float* __restrict__ cst, u16* __restrict__ hid0,
    float* __restrict__ ph, unsigned int* __restrict__ cnt)
{
    int i = blockIdx.x * 256 + threadIdx.x;   // grid covers 2,097,152

    // Wcat [2048][1024] interleaved row np=4h+g: [W_ih[:, :512] | W_hh]
    {
        int np = i >> 10, k = i & (XK2 - 1);
        int h = np >> 2, g = np & 3;
        int n = g * HH + h;
        float v = (k < 512) ? W_ih[(size_t)n * (DIN + EE) + k]
                            : W_hh[(size_t)n * HH + (k - 512)];
        Wcat[(size_t)i] = f2bf(v);
    }
    // Wce16 [2048][256] interleaved: W_ih[:, 512:768]
    if (i < G4 * EE) {
        int np = i >> 8, e = i & (EE - 1);
        int h = np >> 2, g = np & 3;
        int n = g * HH + h;
        Wce16[i] = f2bf(W_ih[(size_t)n * (DIN + EE) + DIN + e]);
    }
    // emb16 [128][256], rows >= 97 zeroed
    if (i < 128 * EE) {
        int ch = i >> 8, e = i & (EE - 1);
        emb16[i] = (ch < CC) ? f2bf(emb[(size_t)ch * EE + e]) : (u16)0;
    }
    // Wgen16 [128][512], rows >= 97 zeroed
    if (i < 128 * HH) {
        int n = i >> 9, k = i & (HH - 1);
        Wgen16[i] = (n < CC) ? f2bf(W_gen[(size_t)n * HH + k]) : (u16)0;
    }
    // Wi2h16, Wh2h16 plain casts
    if (i < HH * DIN) Wi2h16[i] = f2bf(W_i2h[i]);
    if (i < HH * HH)  Wh2h16[i] = f2bf(W_h2h[i]);
    // bcat interleaved
    if (i < G4) {
        int h = i >> 2, g = i & 3;
        int n = g * HH + h;
        bcat[i] = b_ih[n] + b_hh[n];
    }
    // state init: c=0, hid slot0 = 0, ph = b_h2h (h0 = 0)
    if (i < BB * HH) {
        cst[i] = 0.0f;
        hid0[i] = 0;
        ph[i] = b_h2h[i & (HH - 1)];
    }
    // per-step strip arrive counters
    if (i < SS * 32) cnt[i] = 0u;
}

// ---------------------------------------------------------------------------
// Workspace layout (bytes)
// ---------------------------------------------------------------------------
#define BH16_OFF  ((size_t)0)             // bf16 [B*T, DIN]   54,525,952
#define HP_OFF    ((size_t)54525952)      // bf16 [B*T, H]     54,525,952
#define HID_OFF   ((size_t)109051904)     // bf16 [33][B][H]   69,206,016
#define CTX_OFF   ((size_t)178257920)     // bf16 [B][512]      2,097,152
#define WCAT_OFF  ((size_t)180355072)     // bf16 [2048][1024]  4,194,304
#define WCE_OFF   ((size_t)184549376)     // bf16 [2048][256]   1,048,576
#define EMB16_OFF ((size_t)185597952)     // bf16 [128][256]       65,536
#define WGEN_OFF  ((size_t)185663488)     // bf16 [128][512]      131,072
#define WI2H_OFF  ((size_t)185794560)     // bf16 [512][512]      524,288
#define WH2H_OFF  ((size_t)186318848)     // bf16 [512][512]      524,288
#define BCAT_OFF  ((size_t)186843136)     // f32 [2048]             8,192
#define P_OFF     ((size_t)186851328)     // f32 [128][2048]    1,048,576
#define PH_OFF    ((size_t)187899904)     // f32 [B][512]       4,194,304
#define CST_OFF   ((size_t)192094208)     // f32 [B][512]       4,194,304
#define CNT_OFF   ((size_t)196288512)     // u32 [SS][32]           4,096

extern "C" void kernel_launch(void* const* d_in, const int* in_sizes, int n_in,
                              void* d_out, int out_size, void* d_ws, size_t ws_size,
                              hipStream_t stream)
{
    const float* batch_H = (const float*)d_in[0];
    const int*   text    = (const int*)d_in[1];
    const float* W_i2h   = (const float*)d_in[2];
    const float* W_h2h   = (const float*)d_in[3];
    const float* b_h2h   = (const float*)d_in[4];
    const float* w_score = (const float*)d_in[5];
    const float* W_ih    = (const float*)d_in[6];
    const float* W_hh    = (const float*)d_in[7];
    const float* b_ih    = (const float*)d_in[8];
    const float* b_hh    = (const float*)d_in[9];
    const float* W_gen   = (const float*)d_in[10];
    const float* b_gen   = (const float*)d_in[11];
    const float* emb     = (const float*)d_in[12];

    char* ws = (char*)d_ws;
    u16*   bH16   = (u16*)(ws + BH16_OFF);
    u16*   Hp     = (u16*)(ws + HP_OFF);
    u16*   hid    = (u16*)(ws + HID_OFF);
    u16*   ctx    = (u16*)(ws + CTX_OFF);
    u16*   Wcat   = (u16*)(ws + WCAT_OFF);
    u16*   Wce16  = (u16*)(ws + WCE_OFF);
    u16*   emb16  = (u16*)(ws + EMB16_OFF);
    u16*   Wgen16 = (u16*)(ws + WGEN_OFF);
    u16*   Wi2h16 = (u16*)(ws + WI2H_OFF);
    u16*   Wh2h16 = (u16*)(ws + WH2H_OFF);
    float* bcat   = (float*)(ws + BCAT_OFF);
    float* P      = (float*)(ws + P_OFF);
    float* ph     = (float*)(ws + PH_OFF);
    float* cst    = (float*)(ws + CST_OFF);
    unsigned int* cnt = (unsigned int*)(ws + CNT_OFF);
    float* out    = (float*)d_out;

    // prep (3 launches)
    cast_f32_bf16<<<dim3((BB * TT * DIN / 4 + 255) / 256), 256, 0, stream>>>(
        batch_H, bH16, BB * TT * DIN);
    prep_all<<<dim3((G4 * XK2) / 256), 256, 0, stream>>>(
        W_ih, W_hh, b_ih, b_hh, b_h2h, emb, W_i2h, W_h2h, W_gen,
        Wcat, Wce16, emb16, Wgen16, Wi2h16, Wh2h16, bcat, cst, hid, ph, cnt);
    // P[128][2048] = emb16 @ Wce16^T  (fp32 out)
    gemm64<<<dim3(G4 / 64, 128 / 64), 256, 0, stream>>>(
        emb16, EE, Wce16, EE, nullptr, P, G4, EE, 0);

    // Hp = batch_H @ W_i2h^T
    gemm128<<<dim3(HH / 128, (BB * TT) / 128), 256, 0, stream>>>(
        bH16, DIN, Wi2h16, Hp, HH, DIN);

    for (int s = 0; s < SS; s++) {
        u16* hprev = hid + (size_t)s * BB * HH;
        u16* hnext = hid + (size_t)(s + 1) * BB * HH;

        attn_step<<<dim3(BB), 256, 0, stream>>>(Hp, ph, w_score, bH16, ctx);

        // gates + fused LSTM + fused ph (for step s+1)
        gates_lstm<<<dim3(G4 / 128, BB / 64), 256, 0, stream>>>(
            ctx, hprev, Wcat, bcat, P, text, cst, hnext, s,
            Wh2h16, b_h2h, ph, cnt);
    }

    // probs = hid[1..32] @ W_gen^T + b_gen  (one big GEMM, scatter store)
    gen128<<<dim3(1, (SS * BB) / 128), 256, 0, stream>>>(
        hid + (size_t)BB * HH, Wgen16, b_gen, out);
}

// Round 11
// 1583.941 us; speedup vs baseline: 2.6437x; 2.6437x over previous
//
#include <hip/hip_runtime.h>

// Problem constants
#define BB 2048
#define TT 26
#define DIN 512
#define HH 512
#define EE 256
#define CC 97
#define SS 32
#define G4 2048   // 4*H
#define XK2 1024  // gates GEMM K: ctx(512) + h(512); ce folded into P lookup

typedef unsigned short u16;
typedef __bf16 bf16x8 __attribute__((ext_vector_type(8)));
typedef float f32x4 __attribute__((ext_vector_type(4)));

__device__ __forceinline__ float bf2f(u16 u) {
    return __uint_as_float(((unsigned int)u) << 16);
}
__device__ __forceinline__ u16 f2bf(float f) {  // RNE
    unsigned int u = __float_as_uint(f);
    u = u + 0x7FFFu + ((u >> 16) & 1u);
    return (u16)(u >> 16);
}
__device__ __forceinline__ float th_f(float x) {
    return 1.0f - 2.0f * __builtin_amdgcn_rcpf(__expf(2.0f * x) + 1.0f);
}
__device__ __forceinline__ float sig_f(float x) {
    return __builtin_amdgcn_rcpf(1.0f + __expf(-x));
}

// async global->LDS, 16B/lane; LDS base wave-uniform
__device__ __forceinline__ void async16(const u16* g, u16* l) {
    __builtin_amdgcn_global_load_lds(
        (const __attribute__((address_space(1))) unsigned int*)(g),
        (__attribute__((address_space(3))) unsigned int*)(l), 16, 0, 0);
}

// ---------------------------------------------------------------------------
// gemm128 (Hp): C[M,N] = A[M,K] @ W[N,K]^T, 128x128 tile, m97 staging, bf16
// out.  XCD-chunked bijective swizzle (grid (4,416)).  BK=64 (r9-verified).
// ---------------------------------------------------------------------------
__global__ __launch_bounds__(256) void gemm128(
    const u16* __restrict__ A, int lda,
    const u16* __restrict__ W,
    u16* __restrict__ Cout, int ldc, int K)
{
    __shared__ __align__(16) u16 As[2 * 128 * 32];   // 16 KB
    __shared__ __align__(16) u16 Ws[2 * 128 * 32];   // 16 KB

    const int tid  = threadIdx.x;
    const int lane = tid & 63;
    const int wave = tid >> 6;

    int b = blockIdx.y * 4 + blockIdx.x;        // grid (4,416)
    int swz = (b & 7) * 208 + (b >> 3);         // XCD-chunked, bijective
    const int m0 = (swz >> 2) * 128;
    const int n0 = (swz & 3) * 128;

    const int srow = tid >> 2;
    const int scol = (tid & 3) * 8;
    const u16* Arow0 = A + (size_t)(m0 + srow) * lda + scol;
    const u16* Arow1 = A + (size_t)(m0 + 64 + srow) * lda + scol;
    const u16* Wrow0 = W + (size_t)(n0 + srow) * K + scol;
    const u16* Wrow1 = W + (size_t)(n0 + 64 + srow) * K + scol;

    const int wm = (wave >> 1) * 64;
    const int wn = (wave & 1) * 64;
    const int fr = lane & 15;
    const int fq = lane >> 4;

    f32x4 acc[4][4];
    #pragma unroll
    for (int i = 0; i < 4; i++)
        #pragma unroll
        for (int j = 0; j < 4; j++)
            #pragma unroll
            for (int r = 0; r < 4; r++) acc[i][j][r] = 0.0f;

    for (int kb = 0; kb < K; kb += 64) {
        #pragma unroll
        for (int cc = 0; cc < 2; cc++) {
            int k0 = kb + cc * 32;
            async16(Arow0 + k0, As + cc * 4096 + wave * 512);
            async16(Arow1 + k0, As + cc * 4096 + 2048 + wave * 512);
            async16(Wrow0 + k0, Ws + cc * 4096 + wave * 512);
            async16(Wrow1 + k0, Ws + cc * 4096 + 2048 + wave * 512);
        }
        __syncthreads();
        #pragma unroll
        for (int cc = 0; cc < 2; cc++) {
            const u16* A_ = As + cc * 4096;
            const u16* W_ = Ws + cc * 4096;
            bf16x8 af[4], bw[4];
            #pragma unroll
            for (int i = 0; i < 4; i++)
                af[i] = *(const bf16x8*)&A_[(wm + i * 16 + fr) * 32 + fq * 8];
            #pragma unroll
            for (int j = 0; j < 4; j++)
                bw[j] = *(const bf16x8*)&W_[(wn + j * 16 + fr) * 32 + fq * 8];
            #pragma unroll
            for (int i = 0; i < 4; i++)
                #pragma unroll
                for (int j = 0; j < 4; j++)
                    acc[i][j] = __builtin_amdgcn_mfma_f32_16x16x32_bf16(
                        af[i], bw[j], acc[i][j], 0, 0, 0);
        }
        __syncthreads();
    }

    #pragma unroll
    for (int j = 0; j < 4; j++) {
        int col = n0 + wn + j * 16 + fr;
        #pragma unroll
        for (int i = 0; i < 4; i++) {
            int row = m0 + wm + i * 16 + fq * 4;
            #pragma unroll
            for (int r = 0; r < 4; r++)
                Cout[(size_t)(row + r) * ldc + col] = f2bf(acc[i][j][r]);
        }
    }
}

// ---------------------------------------------------------------------------
// gen128: probs = hid[1..32] @ Wgen^T + b_gen.  grid (1, 512).  BK=64.
// ---------------------------------------------------------------------------
__global__ __launch_bounds__(256) void gen128(
    const u16* __restrict__ A,
    const u16* __restrict__ Wg,
    const float* __restrict__ bgen,
    float* __restrict__ out)
{
    __shared__ __align__(16) u16 As[2 * 128 * 32];   // 16 KB
    __shared__ __align__(16) u16 Ws[2 * 128 * 32];   // 16 KB

    const int tid  = threadIdx.x;
    const int lane = tid & 63;
    const int wave = tid >> 6;
    const int m0 = blockIdx.y * 128;

    const int srow = tid >> 2;
    const int scol = (tid & 3) * 8;
    const u16* Arow0 = A + (size_t)(m0 + srow) * HH + scol;
    const u16* Arow1 = A + (size_t)(m0 + 64 + srow) * HH + scol;
    const u16* Wrow0 = Wg + (size_t)srow * HH + scol;
    const u16* Wrow1 = Wg + (size_t)(64 + srow) * HH + scol;

    const int wm = (wave >> 1) * 64;
    const int wn = (wave & 1) * 64;
    const int fr = lane & 15;
    const int fq = lane >> 4;

    f32x4 acc[4][4];
    #pragma unroll
    for (int i = 0; i < 4; i++)
        #pragma unroll
        for (int j = 0; j < 4; j++)
            #pragma unroll
            for (int r = 0; r < 4; r++) acc[i][j][r] = 0.0f;

    #pragma unroll
    for (int kb = 0; kb < HH; kb += 64) {
        #pragma unroll
        for (int cc = 0; cc < 2; cc++) {
            int k0 = kb + cc * 32;
            async16(Arow0 + k0, As + cc * 4096 + wave * 512);
            async16(Arow1 + k0, As + cc * 4096 + 2048 + wave * 512);
            async16(Wrow0 + k0, Ws + cc * 4096 + wave * 512);
            async16(Wrow1 + k0, Ws + cc * 4096 + 2048 + wave * 512);
        }
        __syncthreads();
        #pragma unroll
        for (int cc = 0; cc < 2; cc++) {
            const u16* A_ = As + cc * 4096;
            const u16* W_ = Ws + cc * 4096;
            bf16x8 af[4], bw[4];
            #pragma unroll
            for (int i = 0; i < 4; i++)
                af[i] = *(const bf16x8*)&A_[(wm + i * 16 + fr) * 32 + fq * 8];
            #pragma unroll
            for (int j = 0; j < 4; j++)
                bw[j] = *(const bf16x8*)&W_[(wn + j * 16 + fr) * 32 + fq * 8];
            #pragma unroll
            for (int i = 0; i < 4; i++)
                #pragma unroll
                for (int j = 0; j < 4; j++)
                    acc[i][j] = __builtin_amdgcn_mfma_f32_16x16x32_bf16(
                        af[i], bw[j], acc[i][j], 0, 0, 0);
        }
        __syncthreads();
    }

    #pragma unroll
    for (int j = 0; j < 4; j++) {
        int col = wn + j * 16 + fr;
        if (col < CC) {
            float bv = bgen[col];
            #pragma unroll
            for (int i = 0; i < 4; i++) {
                int row = m0 + wm + i * 16 + fq * 4;
                #pragma unroll
                for (int r = 0; r < 4; r++) {
                    int m = row + r;
                    int s = m >> 11, b = m & (BB - 1);
                    out[(size_t)b * (SS * CC) + s * CC + col] = acc[i][j][r] + bv;
                }
            }
        }
    }
}

// ---------------------------------------------------------------------------
// gates_lstm: gates = [ctx|h_s] @ Wcat^T (interleaved col=4h+g), epilogue adds
// bcat + P[char] and applies LSTM.  Tile 64(M)x128(N), grid (16,32)=512,
// 2 blocks/CU.  BK=128 (r8-verified), barriers 16.  gsm aliases staging LDS.
// BK=256 would need 96KB -> occupancy cliff; this is the LDS-capacity limit.
// ---------------------------------------------------------------------------
__global__ __launch_bounds__(256) void gates_lstm(
    const u16* __restrict__ ctx,    // [B][512]
    const u16* __restrict__ hprev,  // [B][512] (hid slot s)
    const u16* __restrict__ Wc,     // [2048][1024] interleaved
    const float* __restrict__ bcat, // [2048] interleaved
    const float* __restrict__ P,    // [128][2048] char-gate bias, interleaved
    const int* __restrict__ text,   // [B][SS]
    float* __restrict__ c,          // [B][512]
    u16* __restrict__ hnext,        // [B][512] (hid slot s+1)
    int s)
{
    // staging: As[4][64*32] 16KB @0 | Ws[4][128*32] 32KB @16384; total 48KB.
    // epilogue: gsm[64][68] f32 (17408B) aliases the base after staging dies.
    __shared__ __align__(16) char smem[49152];
    __shared__ int text_sm[64];

    u16* As = (u16*)smem;
    u16* Ws = (u16*)(smem + 16384);

    const int tid  = threadIdx.x;
    const int lane = tid & 63;
    const int wave = tid >> 6;

    // XCD swizzle: per-XCD 8x8 region (A 8 strips + W 8 strips < 4 MB L2)
    int b   = blockIdx.y * gridDim.x + blockIdx.x;
    int xcd = b & 7, loc = b >> 3;
    int by = (xcd & 3) * 8 + (loc & 7);     // 0..31  (M tiles)
    int bx = (xcd >> 2) * 8 + (loc >> 3);   // 0..15  (N tiles)
    const int m0 = by * 64;
    const int n0 = bx * 128;

    if (tid < 64) text_sm[tid] = text[(m0 + tid) * SS + s];

    const int srow = tid >> 2;
    const int scol = (tid & 3) * 8;
    const u16* Actx  = ctx   + (size_t)(m0 + srow) * 512 + scol;
    const u16* Ahid  = hprev + (size_t)(m0 + srow) * 512 + scol;
    const u16* Wrow0 = Wc + (size_t)(n0 + srow) * XK2 + scol;
    const u16* Wrow1 = Wc + (size_t)(n0 + 64 + srow) * XK2 + scol;

    const int wm = (wave & 1) * 32;   // 2x2 wave grid: 32M x 64N each
    const int wn = (wave >> 1) * 64;
    const int fr = lane & 15;
    const int fq = lane >> 4;

    f32x4 acc[2][4];
    #pragma unroll
    for (int i = 0; i < 2; i++)
        #pragma unroll
        for (int j = 0; j < 4; j++)
            #pragma unroll
            for (int r = 0; r < 4; r++) acc[i][j][r] = 0.0f;

    #pragma unroll
    for (int it = 0; it < 8; it++) {
        int kb = it * 128;
        #pragma unroll
        for (int cc = 0; cc < 4; cc++) {
            int k0 = kb + cc * 32;
            const u16* a = (k0 < 512) ? (Actx + k0) : (Ahid + (k0 - 512));
            async16(a, As + cc * 2048 + wave * 512);
            async16(Wrow0 + k0, Ws + cc * 4096 + wave * 512);
            async16(Wrow1 + k0, Ws + cc * 4096 + 2048 + wave * 512);
        }
        __syncthreads();
        #pragma unroll
        for (int cc = 0; cc < 4; cc++) {
            const u16* A_ = As + cc * 2048;
            const u16* W_ = Ws + cc * 4096;
            bf16x8 af[2], bw[4];
            #pragma unroll
            for (int i = 0; i < 2; i++)
                af[i] = *(const bf16x8*)&A_[(wm + i * 16 + fr) * 32 + fq * 8];
            #pragma unroll
            for (int j = 0; j < 4; j++)
                bw[j] = *(const bf16x8*)&W_[(wn + j * 16 + fr) * 32 + fq * 8];
            #pragma unroll
            for (int i = 0; i < 2; i++)
                #pragma unroll
                for (int j = 0; j < 4; j++)
                    acc[i][j] = __builtin_amdgcn_mfma_f32_16x16x32_bf16(
                        af[i], bw[j], acc[i][j], 0, 0, 0);
        }
        __syncthreads();
    }

    // Epilogue: two 64-col passes -> gsm (aliases staging), then fused LSTM
    float* gsm = (float*)smem;
    #pragma unroll
    for (int p = 0; p < 2; p++) {
        if ((wave >> 1) == p) {
            #pragma unroll
            for (int j = 0; j < 4; j++) {
                int cl = j * 16 + fr;
                #pragma unroll
                for (int i = 0; i < 2; i++) {
                    int rl = wm + i * 16 + fq * 4;
                    #pragma unroll
                    for (int r = 0; r < 4; r++)
                        gsm[(rl + r) * 68 + cl] = acc[i][j][r];
                }
            }
        }
        __syncthreads();
        #pragma unroll
        for (int rr = 0; rr < 4; rr++) {
            int idx = rr * 256 + tid;
            int u = idx & 15, row = idx >> 4;
            int base = row * 68 + 4 * u;
            int hg = (n0 >> 2) + p * 16 + u;   // global h unit
            int c0 = 4 * hg;                    // interleaved gate col base
            int ch = text_sm[row];
            float4 bc = *(const float4*)(bcat + c0);
            float4 pv = *(const float4*)(P + (size_t)ch * G4 + c0);
            float ig = sig_f(gsm[base]     + bc.x + pv.x);
            float fg = sig_f(gsm[base + 1] + bc.y + pv.y);
            float gg = th_f (gsm[base + 2] + bc.z + pv.z);
            float og = sig_f(gsm[base + 3] + bc.w + pv.w);
            size_t ci = (size_t)(m0 + row) * HH + hg;
            float cn = fg * c[ci] + ig * gg;
            c[ci] = cn;
            hnext[(size_t)(m0 + row) * HH + hg] = f2bf(og * th_f(cn));
        }
        __syncthreads();
    }
}

// ---------------------------------------------------------------------------
// ph64: ph = hnext @ W_h2h^T + b_h2h.  M=2048 N=512 K=512, 64x64 tile,
// grid 256 flat.  global_load_lds staging + XCD swizzle (r6-verified).
// BK=128 (r9-verified), barriers 8.
// ---------------------------------------------------------------------------
__global__ __launch_bounds__(256) void ph64(
    const u16* __restrict__ A,       // hnext [2048][512]
    const u16* __restrict__ W,       // Wh2h16 [512][512]
    const float* __restrict__ bias,  // b_h2h [512]
    float* __restrict__ out)         // ph [2048][512] f32
{
    __shared__ __align__(16) u16 As[4 * 64 * 32];   // 16 KB
    __shared__ __align__(16) u16 Ws[4 * 64 * 32];   // 16 KB

    const int tid  = threadIdx.x;
    const int lane = tid & 63;
    const int wave = tid >> 6;

    int b   = blockIdx.x;                 // 0..255
    int swz = (b & 7) * 32 + (b >> 3);    // bijective (256 = 8*32)
    const int m0 = (swz >> 3) * 64;       // 32 M-tiles
    const int n0 = (swz & 7) * 64;        // 8 N-tiles

    const int srow = tid >> 2;
    const int scol = (tid & 3) * 8;
    const u16* Arow = A + (size_t)(m0 + srow) * HH + scol;
    const u16* Wrow = W + (size_t)(n0 + srow) * HH + scol;

    const int wm = (wave >> 1) * 32;
    const int wn = (wave & 1) * 32;
    const int fr = lane & 15;
    const int fq = lane >> 4;

    f32x4 acc[2][2];
    #pragma unroll
    for (int i = 0; i < 2; i++)
        #pragma unroll
        for (int j = 0; j < 2; j++)
            #pragma unroll
            for (int r = 0; r < 4; r++) acc[i][j][r] = 0.0f;

    #pragma unroll
    for (int it = 0; it < 4; it++) {
        int kb = it * 128;
        #pragma unroll
        for (int cc = 0; cc < 4; cc++) {
            int k0 = kb + cc * 32;
            async16(Arow + k0, As + cc * 2048 + wave * 512);
            async16(Wrow + k0, Ws + cc * 2048 + wave * 512);
        }
        __syncthreads();
        #pragma unroll
        for (int cc = 0; cc < 4; cc++) {
            const u16* A_ = As + cc * 2048;
            const u16* W_ = Ws + cc * 2048;
            bf16x8 af[2], bw[2];
            #pragma unroll
            for (int mm = 0; mm < 2; mm++)
                af[mm] = *(const bf16x8*)&A_[(wm + mm * 16 + fr) * 32 + fq * 8];
            #pragma unroll
            for (int nn = 0; nn < 2; nn++)
                bw[nn] = *(const bf16x8*)&W_[(wn + nn * 16 + fr) * 32 + fq * 8];
            #pragma unroll
            for (int mm = 0; mm < 2; mm++)
                #pragma unroll
                for (int nn = 0; nn < 2; nn++)
                    acc[mm][nn] = __builtin_amdgcn_mfma_f32_16x16x32_bf16(
                        af[mm], bw[nn], acc[mm][nn], 0, 0, 0);
        }
        __syncthreads();
    }

    #pragma unroll
    for (int nn = 0; nn < 2; nn++) {
        int col = n0 + wn + nn * 16 + fr;
        float bv = bias[col];
        #pragma unroll
        for (int mm = 0; mm < 2; mm++) {
            int row = m0 + wm + mm * 16 + fq * 4;
            #pragma unroll
            for (int r = 0; r < 4; r++)
                out[(size_t)(row + r) * HH + col] = acc[mm][nn][r] + bv;
        }
    }
}

// ---------------------------------------------------------------------------
// gemm64: generic 64x64-tile GEMM (VGPR-staged).  One-time P build only.
// ---------------------------------------------------------------------------
__global__ __launch_bounds__(256) void gemm64(
    const u16* __restrict__ A, int lda,
    const u16* __restrict__ W, int ldw,
    const float* __restrict__ bias,
    float* __restrict__ Cout, int ldc, int K, int use_bias)
{
    __shared__ __align__(16) u16 As[64][32];
    __shared__ __align__(16) u16 Ws[64][32];

    const int tid  = threadIdx.x;
    const int lane = tid & 63;
    const int wave = tid >> 6;
    const int m0 = blockIdx.y * 64;
    const int n0 = blockIdx.x * 64;
    const int ar = tid >> 2;
    const int ac = (tid & 3) * 8;
    const int wm = (wave >> 1) * 32;
    const int wn = (wave & 1) * 32;
    const int fr = lane & 15;
    const int fq = lane >> 4;

    f32x4 acc[2][2];
    #pragma unroll
    for (int i = 0; i < 2; i++)
        #pragma unroll
        for (int j = 0; j < 2; j++)
            #pragma unroll
            for (int r = 0; r < 4; r++) acc[i][j][r] = 0.0f;

    const u16* Arow = A + (size_t)(m0 + ar) * lda;
    const u16* Wrow = W + (size_t)(n0 + ar) * ldw;

    for (int k0 = 0; k0 < K; k0 += 32) {
        *(uint4*)&As[ar][ac] = *(const uint4*)(Arow + k0 + ac);
        *(uint4*)&Ws[ar][ac] = *(const uint4*)(Wrow + k0 + ac);
        __syncthreads();
        bf16x8 af[2], bw[2];
        #pragma unroll
        for (int mm = 0; mm < 2; mm++)
            af[mm] = *(const bf16x8*)&As[wm + mm * 16 + fr][fq * 8];
        #pragma unroll
        for (int nn = 0; nn < 2; nn++)
            bw[nn] = *(const bf16x8*)&Ws[wn + nn * 16 + fr][fq * 8];
        #pragma unroll
        for (int mm = 0; mm < 2; mm++)
            #pragma unroll
            for (int nn = 0; nn < 2; nn++)
                acc[mm][nn] = __builtin_amdgcn_mfma_f32_16x16x32_bf16(
                    af[mm], bw[nn], acc[mm][nn], 0, 0, 0);
        __syncthreads();
    }

    #pragma unroll
    for (int nn = 0; nn < 2; nn++) {
        int col = n0 + wn + nn * 16 + fr;
        float bv = use_bias ? bias[col] : 0.0f;
        #pragma unroll
        for (int mm = 0; mm < 2; mm++) {
            int row = m0 + wm + mm * 16 + fq * 4;
            #pragma unroll
            for (int r = 0; r < 4; r++)
                Cout[(size_t)(row + r) * ldc + col] = acc[mm][nn][r] + bv;
        }
    }
}

// ---------------------------------------------------------------------------
// attn_step: e/softmax/context into ctx buffer.  1 block / batch row.
// (r2-verified: wave-parallel softmax, direct phase C)
// ---------------------------------------------------------------------------
__global__ __launch_bounds__(256) void attn_step(
    const u16* __restrict__ Hp, const float* __restrict__ ph,
    const float* __restrict__ wscore, const u16* __restrict__ bH16,
    u16* __restrict__ ctx)
{
    const int b = blockIdx.x;
    const int tid = threadIdx.x, lane = tid & 63, wave = tid >> 6;
    __shared__ float e_sm[32];
    __shared__ float alpha_sm[32];

    const int h8 = lane * 8;
    float ph_r[8], ws_r[8];
    {
        float4 p0 = *(const float4*)(ph + (size_t)b * HH + h8);
        float4 p1 = *(const float4*)(ph + (size_t)b * HH + h8 + 4);
        ph_r[0]=p0.x; ph_r[1]=p0.y; ph_r[2]=p0.z; ph_r[3]=p0.w;
        ph_r[4]=p1.x; ph_r[5]=p1.y; ph_r[6]=p1.z; ph_r[7]=p1.w;
        float4 w0 = *(const float4*)(wscore + h8);
        float4 w1 = *(const float4*)(wscore + h8 + 4);
        ws_r[0]=w0.x; ws_r[1]=w0.y; ws_r[2]=w0.z; ws_r[3]=w0.w;
        ws_r[4]=w1.x; ws_r[5]=w1.y; ws_r[6]=w1.z; ws_r[7]=w1.w;
    }

    for (int t = wave; t < TT; t += 4) {
        uint4 hv = *(const uint4*)(Hp + ((size_t)b * TT + t) * HH + h8);
        const u16* hu = (const u16*)&hv;
        float sum = 0.0f;
        #pragma unroll
        for (int j = 0; j < 8; j++)
            sum += th_f(bf2f(hu[j]) + ph_r[j]) * ws_r[j];
        #pragma unroll
        for (int off = 32; off > 0; off >>= 1) sum += __shfl_down(sum, off);
        if (lane == 0) e_sm[t] = sum;
    }
    __syncthreads();

    // wave-parallel softmax over t (wave 0 only)
    if (wave == 0) {
        float ev = (lane < TT) ? e_sm[lane] : -3.0e38f;
        float mx = ev;
        #pragma unroll
        for (int off = 32; off > 0; off >>= 1)
            mx = fmaxf(mx, __shfl_xor(mx, off));
        float p = (lane < TT) ? __expf(ev - mx) : 0.0f;
        float ssum = p;
        #pragma unroll
        for (int off = 32; off > 0; off >>= 1) ssum += __shfl_xor(ssum, off);
        if (lane < TT) alpha_sm[lane] = p / ssum;
    }
    __syncthreads();

    {
        int d0 = tid * 2;
        float c0 = 0.0f, c1 = 0.0f;
        const u16* bb = bH16 + (size_t)b * TT * DIN + d0;
        #pragma unroll
        for (int t = 0; t < TT; t++) {
            unsigned int v = *(const unsigned int*)(bb + (size_t)t * DIN);
            float a = alpha_sm[t];
            c0 += a * bf2f((u16)(v & 0xffffu));
            c1 += a * bf2f((u16)(v >> 16));
        }
        unsigned int o = (unsigned int)f2bf(c0) | ((unsigned int)f2bf(c1) << 16);
        *(unsigned int*)(ctx + (size_t)b * 512 + d0) = o;
    }
}

// ---------------------------------------------------------------------------
// prep: bH16 cast (separate, big) + prep_all (everything else, one launch)
// ---------------------------------------------------------------------------
__global__ __launch_bounds__(256) void cast_f32_bf16(
    const float* __restrict__ src, u16* __restrict__ dst, int n)
{
    int i = (blockIdx.x * 256 + threadIdx.x) * 4;
    if (i < n) {
        float4 v = *(const float4*)(src + i);
        ushort4 o;
        o.x = f2bf(v.x); o.y = f2bf(v.y); o.z = f2bf(v.z); o.w = f2bf(v.w);
        *(ushort4*)(dst + i) = o;
    }
}

__global__ __launch_bounds__(256) void prep_all(
    const float* __restrict__ W_ih, const float* __restrict__ W_hh,
    const float* __restrict__ b_ih, const float* __restrict__ b_hh,
    const float* __restrict__ b_h2h, const float* __restrict__ emb,
    const float* __restrict__ W_i2h, const float* __restrict__ W_h2h,
    const float* __restrict__ W_gen,
    u16* __restrict__ Wcat, u16* __restrict__ Wce16, u16* __restrict__ emb16,
    u16* __restrict__ Wgen16, u16* __restrict__ Wi2h16, u16* __restrict__ Wh2h16,
    float* __restrict__ bcat, float* __restrict__ cst, u16* __restrict__ hid0,
    float* __restrict__ ph)
{
    int i = blockIdx.x * 256 + threadIdx.x;   // grid covers 2,097,152

    // Wcat [2048][1024] interleaved row np=4h+g: [W_ih[:, :512] | W_hh]
    {
        int np = i >> 10, k = i & (XK2 - 1);
        int h = np >> 2, g = np & 3;
        int n = g * HH + h;
        float v = (k < 512) ? W_ih[(size_t)n * (DIN + EE) + k]
                            : W_hh[(size_t)n * HH + (k - 512)];
        Wcat[(size_t)i] = f2bf(v);
    }
    // Wce16 [2048][256] interleaved: W_ih[:, 512:768]
    if (i < G4 * EE) {
        int np = i >> 8, e = i & (EE - 1);
        int h = np >> 2, g = np & 3;
        int n = g * HH + h;
        Wce16[i] = f2bf(W_ih[(size_t)n * (DIN + EE) + DIN + e]);
    }
    // emb16 [128][256], rows >= 97 zeroed
    if (i < 128 * EE) {
        int ch = i >> 8, e = i & (EE - 1);
        emb16[i] = (ch < CC) ? f2bf(emb[(size_t)ch * EE + e]) : (u16)0;
    }
    // Wgen16 [128][512], rows >= 97 zeroed
    if (i < 128 * HH) {
        int n = i >> 9, k = i & (HH - 1);
        Wgen16[i] = (n < CC) ? f2bf(W_gen[(size_t)n * HH + k]) : (u16)0;
    }
    // Wi2h16, Wh2h16 plain casts
    if (i < HH * DIN) Wi2h16[i] = f2bf(W_i2h[i]);
    if (i < HH * HH)  Wh2h16[i] = f2bf(W_h2h[i]);
    // bcat interleaved
    if (i < G4) {
        int h = i >> 2, g = i & 3;
        int n = g * HH + h;
        bcat[i] = b_ih[n] + b_hh[n];
    }
    // state init: c=0, hid slot0 = 0, ph = b_h2h (h0 = 0)
    if (i < BB * HH) {
        cst[i] = 0.0f;
        hid0[i] = 0;
        ph[i] = b_h2h[i & (HH - 1)];
    }
}

// ---------------------------------------------------------------------------
// Workspace layout (bytes)
// ---------------------------------------------------------------------------
#define BH16_OFF  ((size_t)0)             // bf16 [B*T, DIN]   54,525,952
#define HP_OFF    ((size_t)54525952)      // bf16 [B*T, H]     54,525,952
#define HID_OFF   ((size_t)109051904)     // bf16 [33][B][H]   69,206,016
#define CTX_OFF   ((size_t)178257920)     // bf16 [B][512]      2,097,152
#define WCAT_OFF  ((size_t)180355072)     // bf16 [2048][1024]  4,194,304
#define WCE_OFF   ((size_t)184549376)     // bf16 [2048][256]   1,048,576
#define EMB16_OFF ((size_t)185597952)     // bf16 [128][256]       65,536
#define WGEN_OFF  ((size_t)185663488)     // bf16 [128][512]      131,072
#define WI2H_OFF  ((size_t)185794560)     // bf16 [512][512]      524,288
#define WH2H_OFF  ((size_t)186318848)     // bf16 [512][512]      524,288
#define BCAT_OFF  ((size_t)186843136)     // f32 [2048]             8,192
#define P_OFF     ((size_t)186851328)     // f32 [128][2048]    1,048,576
#define PH_OFF    ((size_t)187899904)     // f32 [B][512]       4,194,304
#define CST_OFF   ((size_t)192094208)     // f32 [B][512]       4,194,304

extern "C" void kernel_launch(void* const* d_in, const int* in_sizes, int n_in,
                              void* d_out, int out_size, void* d_ws, size_t ws_size,
                              hipStream_t stream)
{
    const float* batch_H = (const float*)d_in[0];
    const int*   text    = (const int*)d_in[1];
    const float* W_i2h   = (const float*)d_in[2];
    const float* W_h2h   = (const float*)d_in[3];
    const float* b_h2h   = (const float*)d_in[4];
    const float* w_score = (const float*)d_in[5];
    const float* W_ih    = (const float*)d_in[6];
    const float* W_hh    = (const float*)d_in[7];
    const float* b_ih    = (const float*)d_in[8];
    const float* b_hh    = (const float*)d_in[9];
    const float* W_gen   = (const float*)d_in[10];
    const float* b_gen   = (const float*)d_in[11];
    const float* emb     = (const float*)d_in[12];

    char* ws = (char*)d_ws;
    u16*   bH16   = (u16*)(ws + BH16_OFF);
    u16*   Hp     = (u16*)(ws + HP_OFF);
    u16*   hid    = (u16*)(ws + HID_OFF);
    u16*   ctx    = (u16*)(ws + CTX_OFF);
    u16*   Wcat   = (u16*)(ws + WCAT_OFF);
    u16*   Wce16  = (u16*)(ws + WCE_OFF);
    u16*   emb16  = (u16*)(ws + EMB16_OFF);
    u16*   Wgen16 = (u16*)(ws + WGEN_OFF);
    u16*   Wi2h16 = (u16*)(ws + WI2H_OFF);
    u16*   Wh2h16 = (u16*)(ws + WH2H_OFF);
    float* bcat   = (float*)(ws + BCAT_OFF);
    float* P      = (float*)(ws + P_OFF);
    float* ph     = (float*)(ws + PH_OFF);
    float* cst    = (float*)(ws + CST_OFF);
    float* out    = (float*)d_out;

    // prep (3 launches)
    cast_f32_bf16<<<dim3((BB * TT * DIN / 4 + 255) / 256), 256, 0, stream>>>(
        batch_H, bH16, BB * TT * DIN);
    prep_all<<<dim3((G4 * XK2) / 256), 256, 0, stream>>>(
        W_ih, W_hh, b_ih, b_hh, b_h2h, emb, W_i2h, W_h2h, W_gen,
        Wcat, Wce16, emb16, Wgen16, Wi2h16, Wh2h16, bcat, cst, hid, ph);
    // P[128][2048] = emb16 @ Wce16^T  (fp32 out)
    gemm64<<<dim3(G4 / 64, 128 / 64), 256, 0, stream>>>(
        emb16, EE, Wce16, EE, nullptr, P, G4, EE, 0);

    // Hp = batch_H @ W_i2h^T
    gemm128<<<dim3(HH / 128, (BB * TT) / 128), 256, 0, stream>>>(
        bH16, DIN, Wi2h16, Hp, HH, DIN);

    for (int s = 0; s < SS; s++) {
        u16* hprev = hid + (size_t)s * BB * HH;
        u16* hnext = hid + (size_t)(s + 1) * BB * HH;

        attn_step<<<dim3(BB), 256, 0, stream>>>(Hp, ph, w_score, bH16, ctx);

        gates_lstm<<<dim3(G4 / 128, BB / 64), 256, 0, stream>>>(
            ctx, hprev, Wcat, bcat, P, text, cst, hnext, s);

        // ph = h_{s+1} @ W_h2h^T + b_h2h
        ph64<<<dim3(256), 256, 0, stream>>>(hnext, Wh2h16, b_h2h, ph);
    }

    // probs = hid[1..32] @ W_gen^T + b_gen  (one big GEMM, scatter store)
    gen128<<<dim3(1, (SS * BB) / 128), 256, 0, stream>>>(
        hid + (size_t)BB * HH, Wgen16, b_gen, out);
}